// Round 15
// baseline (360.896 us; speedup 1.0000x reference)
//
#include <hip/hip_runtime.h>
#include <hip/hip_bf16.h>
#include <cstdint>

// Problem constants
#define EMBED   192
#define DINNER  384
#define DSTATE  4
#define DCONV   4
#define DTRANK  12
#define NMIX    2
#define RANK    4
#define BB      8
#define LL      4096            // H*W = 64*64
#define NBL     (BB*LL)         // 32768 rows
#define NCHUNK  128
#define CLEN    32              // LL / NCHUNK (verified optimum; 16 regressed)
#define RSTR    36              // rows LDS stride (pad: b128-aligned, <=2-way banks)
#define XSTR    392             // xa LDS tile stride (384+8: <=2-way banks)

typedef __attribute__((ext_vector_type(8))) short short8;
typedef __attribute__((ext_vector_type(4))) float float4v;

static __device__ __forceinline__ ushort f2b(float f) {
    __hip_bfloat16 h = __float2bfloat16(f);
    return *(ushort*)&h;
}
static __device__ __forceinline__ float b2f(ushort u) {
    __hip_bfloat16 h;
    *(ushort*)&h = u;
    return __bfloat162float(h);
}
static __device__ __forceinline__ float bs2f(short s) {
    ushort u = (ushort)s;
    return b2f(u);
}

// ---------------------------------------------------------------------------
// Fused weight prep + input transpose (ONE launch):
// blocks [0, PREP_BLKS): wi cast | wo cast | xpw pad | dtw pad | cwT
// blocks [PREP_BLKS, +6144): (B,C,L) -> (B,L,C) bf16 transpose (h0b).
// Branch is block-uniform; __syncthreads only on the transpose path.
// ---------------------------------------------------------------------------
#define PREP_N0 294912
#define PREP_N1 147456
#define PREP_N2 24576
#define PREP_N3 24576
#define PREP_N4 3072
#define PREP_BLKS ((PREP_N0 + PREP_N1 + PREP_N2 + PREP_N3 + PREP_N4) / 256)   // 1932
#define TRAN_BLKS ((LL / 32) * (EMBED / 32) * BB)                              // 6144
__global__ __launch_bounds__(256) void k_prep(const float* __restrict__ x,
                                              const float* __restrict__ in_proj_w,
                                              const float* __restrict__ out_proj_w,
                                              const float* __restrict__ x_proj_w,
                                              const float* __restrict__ dt_proj_w,
                                              const float* __restrict__ conv_w,
                                              ushort* __restrict__ wi,
                                              ushort* __restrict__ wo,
                                              ushort* __restrict__ xpwb,
                                              ushort* __restrict__ dtwpad,
                                              float* __restrict__ cwt,
                                              ushort* __restrict__ h0b) {
    __shared__ float tile[32][33];
    int bid = blockIdx.x;
    if (bid < PREP_BLKS) {
        int i = bid * 256 + threadIdx.x;
        if (i < PREP_N0) {
            wi[i] = f2b(in_proj_w[i]);
            return;
        }
        i -= PREP_N0;
        if (i < PREP_N1) {
            wo[i] = f2b(out_proj_w[i]);
            return;
        }
        i -= PREP_N1;
        if (i < PREP_N2) {
            int mix = i / (32 * 384);
            int rem = i % (32 * 384);
            int e = rem / 384, k = rem % 384;
            xpwb[i] = (e < 20) ? f2b(x_proj_w[(size_t)mix * 20 * 384 + e * 384 + k])
                               : (ushort)0;
            return;
        }
        i -= PREP_N2;
        if (i < PREP_N3) {
            // dtwpad[mix][d][r], r zero-padded 12..31 (K=32 exact)
            int mix = i / (384 * 32);
            int rem = i % (384 * 32);
            int n = rem / 32, r = rem % 32;
            dtwpad[i] = (r < DTRANK)
                ? f2b(dt_proj_w[(size_t)mix * 384 * DTRANK + n * DTRANK + r])
                : (ushort)0;
            return;
        }
        i -= PREP_N3;
        if (i < PREP_N4) {
            int mix = i / (DCONV * DINNER);
            int rem = i % (DCONV * DINNER);
            int k = rem / DINNER, d = rem % DINNER;
            cwt[i] = conv_w[(size_t)mix * DINNER * DCONV + d * DCONV + k];
        }
        return;
    }
    // transpose path: decode (x=LL/32 fastest, y=EMBED/32, z=BB)
    int tb   = bid - PREP_BLKS;
    int xb   = tb % (LL / 32);
    int rest = tb / (LL / 32);
    int cbk  = rest % (EMBED / 32);
    int b    = rest / (EMBED / 32);
    int l0 = xb * 32;
    int c0 = cbk * 32;
    int tx = threadIdx.x & 31;
    int ty = threadIdx.x >> 5;      // 0..7
    #pragma unroll
    for (int i = 0; i < 4; i++) {
        int c = c0 + ty + i * 8;
        tile[ty + i * 8][tx] = x[((size_t)b * EMBED + c) * LL + l0 + tx];
    }
    __syncthreads();
    #pragma unroll
    for (int i = 0; i < 4; i++) {
        int l = l0 + ty + i * 8;
        h0b[((size_t)b * LL + l) * EMBED + c0 + tx] = f2b(tile[tx][ty + i * 8]);
    }
}

// ---------------------------------------------------------------------------
// bf16 MFMA GEMM, NT: C[m,n] = sum_k A[m,k]*B[n,k]. M=32768.
// Grid dim3(256 m-tiles, NTL n-tiles), M in blockIdx.x: A-panel sharers land
// on the same XCD (bid%8 == M%8 since gridDim.x%8==0) -> panel HBM-fetched
// once per XCD L2 (verified r7: FETCH 76MB -> 11.5MB).
// Reg-prefetch k+1 before the MFMAs + LDS double-buffer, ONE barrier/iter
// (verified r8: 381 -> 369.6).
// TN in {128 (WRN=2), 64 (WRN=1)}. BK=32. Writes bf16 Cb.
// SILUZ: apply silu to cols >= DINNER before the store (pre-gated z).
// ---------------------------------------------------------------------------
template<int TN, int WRN, bool SILUZ>
__global__ __launch_bounds__(256) void k_gemm_bf16(const ushort* __restrict__ A, int lda,
                                                   const ushort* __restrict__ Bw, int ldb,
                                                   ushort* __restrict__ Cb, int ldcb,
                                                   int K) {
    constexpr int WRM = 4 / WRN;
    constexpr int WM  = 128 / WRM;
    constexpr int MT  = WM / 16;
    constexpr int NBU = TN / 64;
    __shared__ ushort As[2][128][40];
    __shared__ ushort Bs[2][TN][40];
    int tid  = threadIdx.x;
    int lane = tid & 63;
    int wave = tid >> 6;
    int mcol = lane & 15;
    int quad = lane >> 4;
    int wmo = (wave / WRN) * WM;
    int wno = (wave % WRN) * 64;
    int m0 = blockIdx.x * 128;
    int n0 = blockIdx.y * TN;

    float4v acc[MT][4];
    #pragma unroll
    for (int i = 0; i < MT; i++)
        #pragma unroll
        for (int j = 0; j < 4; j++)
            acc[i][j] = (float4v){0.f, 0.f, 0.f, 0.f};

    short8 pa[2], pb[NBU];
    // prologue: stage k=0 into buffer 0
    #pragma unroll
    for (int i = 0; i < 2; i++) {
        int idx = tid + i * 256, r = idx >> 2, sg = idx & 3;
        pa[i] = *(const short8*)(A + (size_t)(m0 + r) * lda + sg * 8);
    }
    #pragma unroll
    for (int i = 0; i < NBU; i++) {
        int idx = tid + i * 256, r = idx >> 2, sg = idx & 3;
        pb[i] = *(const short8*)(Bw + (size_t)(n0 + r) * ldb + sg * 8);
    }
    #pragma unroll
    for (int i = 0; i < 2; i++) {
        int idx = tid + i * 256;
        *(short8*)&As[0][idx >> 2][(idx & 3) * 8] = pa[i];
    }
    #pragma unroll
    for (int i = 0; i < NBU; i++) {
        int idx = tid + i * 256;
        *(short8*)&Bs[0][idx >> 2][(idx & 3) * 8] = pb[i];
    }
    __syncthreads();

    int cur = 0;
    for (int k0 = 0; k0 < K; k0 += 32) {
        bool more = (k0 + 32) < K;
        if (more) {
            // issue next-tile loads early: latency hides under ds_read+MFMA
            #pragma unroll
            for (int i = 0; i < 2; i++) {
                int idx = tid + i * 256, r = idx >> 2, sg = idx & 3;
                pa[i] = *(const short8*)(A + (size_t)(m0 + r) * lda + k0 + 32 + sg * 8);
            }
            #pragma unroll
            for (int i = 0; i < NBU; i++) {
                int idx = tid + i * 256, r = idx >> 2, sg = idx & 3;
                pb[i] = *(const short8*)(Bw + (size_t)(n0 + r) * ldb + k0 + 32 + sg * 8);
            }
        }
        short8 av[MT], bv[4];
        #pragma unroll
        for (int i = 0; i < MT; i++)
            av[i] = *(const short8*)&As[cur][wmo + i * 16 + mcol][quad * 8];
        #pragma unroll
        for (int j = 0; j < 4; j++)
            bv[j] = *(const short8*)&Bs[cur][wno + j * 16 + mcol][quad * 8];
        #pragma unroll
        for (int i = 0; i < MT; i++)
            #pragma unroll
            for (int j = 0; j < 4; j++)
                acc[i][j] = __builtin_amdgcn_mfma_f32_16x16x32_bf16(
                    av[i], bv[j], acc[i][j], 0, 0, 0);
        if (more) {
            #pragma unroll
            for (int i = 0; i < 2; i++) {
                int idx = tid + i * 256;
                *(short8*)&As[cur ^ 1][idx >> 2][(idx & 3) * 8] = pa[i];
            }
            #pragma unroll
            for (int i = 0; i < NBU; i++) {
                int idx = tid + i * 256;
                *(short8*)&Bs[cur ^ 1][idx >> 2][(idx & 3) * 8] = pb[i];
            }
        }
        __syncthreads();   // read-done (cur) + write-visible (cur^1), 1/iter
        cur ^= 1;
    }

    #pragma unroll
    for (int i = 0; i < MT; i++) {
        int rbase = m0 + wmo + i * 16 + quad * 4;
        #pragma unroll
        for (int j = 0; j < 4; j++) {
            int col = n0 + wno + j * 16 + mcol;
            #pragma unroll
            for (int r = 0; r < 4; r++) {
                float v = acc[i][j][r];
                if (SILUZ && col >= DINNER) v = v / (1.f + __expf(-v));
                Cb[(size_t)(rbase + r) * ldcb + col] = f2b(v);
            }
        }
    }
}

// ---------------------------------------------------------------------------
// In-block dt tile via MFMA: dt[l][d] = softplus(rows[l][0:12] . dtw[d][0:12]
// + bias[d]), K padded to 32. Result -> LDS bf16.
// ---------------------------------------------------------------------------
static __device__ __forceinline__ void dt_mfma_tile(const float* __restrict__ rows,
                                                    const ushort* __restrict__ dtwpad,
                                                    const float* __restrict__ dtb,
                                                    ushort* __restrict__ dtS,
                                                    int wave, int lane) {
    int mcol = lane & 15;
    int quad = lane >> 4;
    #pragma unroll
    for (int nt = 0; nt < 4; nt++) {
        int n = wave * 64 + nt * 16 + mcol;
        short8 bv = *(const short8*)(dtwpad + (size_t)n * 32 + quad * 8);
        float bias = dtb[n];
        #pragma unroll
        for (int mt = 0; mt < CLEN / 16; mt++) {
            float4v a0 = *(const float4v*)&rows[(mt * 16 + mcol) * RSTR + quad * 8];
            float4v a1 = *(const float4v*)&rows[(mt * 16 + mcol) * RSTR + quad * 8 + 4];
            short8 av;
            #pragma unroll
            for (int j = 0; j < 4; j++) {
                av[j]     = (short)f2b(a0[j]);
                av[j + 4] = (short)f2b(a1[j]);
            }
            float4v acc = (float4v){0.f, 0.f, 0.f, 0.f};
            acc = __builtin_amdgcn_mfma_f32_16x16x32_bf16(av, bv, acc, 0, 0, 0);
            #pragma unroll
            for (int r = 0; r < 4; r++) {
                float s = acc[r] + bias;
                float sp = fmaxf(s, 0.f) + __logf(1.f + __expf(-fabsf(s)));
                dtS[(mt * 16 + quad * 4 + r) * DINNER + n] = f2b(sp);
            }
        }
    }
}

// Adaptive state-decay: if As = (1,2,3,4)*As0 (true for this model's A_log),
// 4 exps collapse to 1 exp + 3 muls. Generic fallback otherwise.
static __device__ __forceinline__ bool as_is_harmonic(const float* As) {
    return fabsf(As[1] - 2.f * As[0]) <= 1e-5f * fabsf(As[1]) + 1e-12f
        && fabsf(As[2] - 3.f * As[0]) <= 1e-5f * fabsf(As[2]) + 1e-12f
        && fabsf(As[3] - 4.f * As[0]) <= 1e-5f * fabsf(As[3]) + 1e-12f;
}

// ---------------------------------------------------------------------------
// Chunked scan pass 1, with conv+silu AND x_proj fused in (r12/r14 form,
// verified 353.3-355.7us). r15: the scan loop's 8 broadcast scalar LDS reads
// of row[12..19] collapse into TWO ds_read_b128 (row+12 and row+16 are both
// 16B-aligned: l*144+48, l*144+64). Bit-identical values, 6 fewer LDS issue
// slots per step.
// ---------------------------------------------------------------------------
__global__ __launch_bounds__(384) void k_scan_local(const ushort* __restrict__ xz,
                                                    const float* __restrict__ cwt,
                                                    const float* __restrict__ cb,
                                                    const ushort* __restrict__ xpwb,
                                                    const ushort* __restrict__ dtwpad,
                                                    const float* __restrict__ dtb,
                                                    const float* __restrict__ A_log,
                                                    const float* __restrict__ Dp,
                                                    float* __restrict__ carryT,
                                                    float* __restrict__ carryH,
                                                    float* __restrict__ ccol,
                                                    uint* __restrict__ dyb) {
    int d     = threadIdx.x;
    int lane  = d & 63;
    int wave  = d >> 6;
    int chunk = blockIdx.x;
    int b     = blockIdx.y;
    __shared__ ushort xaS[CLEN][XSTR];
    __shared__ float rows[CLEN * RSTR];
    __shared__ ushort dtS[CLEN * DINNER];
    size_t mbase = (size_t)b * LL + (size_t)chunk * CLEN;

    // fused conv+silu staging: column d, sliding 4-tap causal window
    {
        float w0 = cwt[0 * DINNER + d], w1 = cwt[1 * DINNER + d];
        float w2 = cwt[2 * DINNER + d], w3 = cwt[3 * DINNER + d];
        float bias = cb[d];
        float r0 = 0.f, r1 = 0.f, r2 = 0.f;
        if (chunk > 0) {
            r0 = b2f(xz[(mbase - 3) * 768 + d]);
            r1 = b2f(xz[(mbase - 2) * 768 + d]);
            r2 = b2f(xz[(mbase - 1) * 768 + d]);
        }
        #pragma unroll 8
        for (int l = 0; l < CLEN; l++) {
            float cur = b2f(xz[(mbase + l) * 768 + d]);
            float a = bias + w0 * r0 + w1 * r1 + w2 * r2 + w3 * cur;
            xaS[l][d] = f2b(a / (1.f + __expf(-a)));
            r0 = r1; r1 = r2; r2 = cur;
        }
    }
    float As[DSTATE];
    #pragma unroll
    for (int s = 0; s < DSTATE; s++) As[s] = -__expf(A_log[d * DSTATE + s]);
    bool fastA = as_is_harmonic(As);
    float Dd = Dp[d];
    __syncthreads();

    // fused x_proj: rows[l][e] = sum_k xaS[l][k] * xpwb[e][k]  (e<32)
    if (wave < (CLEN / 16) * 2) {
        int mi = wave >> 1, ni = wave & 1;
        int mcol = lane & 15, quad = lane >> 4;
        float4v acc = (float4v){0.f, 0.f, 0.f, 0.f};
        #pragma unroll
        for (int k0 = 0; k0 < 384; k0 += 32) {
            short8 av = *(const short8*)&xaS[mi * 16 + mcol][k0 + quad * 8];
            short8 bv = *(const short8*)(xpwb + (size_t)(ni * 16 + mcol) * 384
                                         + k0 + quad * 8);
            acc = __builtin_amdgcn_mfma_f32_16x16x32_bf16(av, bv, acc, 0, 0, 0);
        }
        #pragma unroll
        for (int r = 0; r < 4; r++)
            rows[(mi * 16 + quad * 4 + r) * RSTR + ni * 16 + mcol] = acc[r];
    }
    __syncthreads();
    // compact C-cols for pass 3 (cols 16..19 of rows)
    if (d < CLEN * DSTATE) {
        int l = d >> 2, s = d & 3;
        ccol[(mbase + l) * 4 + s] = rows[l * RSTR + DTRANK + DSTATE + s];
    }
    dt_mfma_tile(rows, dtwpad, dtb, dtS, wave, lane);
    __syncthreads();

    float h[DSTATE] = {0.f, 0.f, 0.f, 0.f};
    float T = 0.f;
    #pragma unroll 8
    for (int l = 0; l < CLEN; l++) {
        ushort dtu = dtS[l * DINNER + d];
        float dtvv = b2f(dtu);
        float xav  = b2f(xaS[l][d]);
        float du   = dtvv * xav;
        T += dtvv;
        const float* row = &rows[l * RSTR];
        float4v bv4 = *(const float4v*)(row + DTRANK);           // B cols 12..15
        float4v cv4 = *(const float4v*)(row + DTRANK + DSTATE);  // C cols 16..19
        float da[DSTATE];
        if (fastA) {
            float p = __expf(dtvv * As[0]);
            da[0] = p; da[1] = p * p; da[2] = da[1] * p; da[3] = da[2] * p;
        } else {
            #pragma unroll
            for (int s = 0; s < DSTATE; s++) da[s] = __expf(dtvv * As[s]);
        }
        float yv = xav * Dd;
        #pragma unroll
        for (int s = 0; s < DSTATE; s++) {
            h[s] = da[s] * h[s] + du * bv4[s];
            yv  += h[s] * cv4[s];
        }
        dyb[(mbase + l) * DINNER + d] = ((uint)dtu << 16) | (uint)f2b(yv);
    }
    size_t cb2 = ((size_t)chunk * BB + b);
    carryT[cb2 * 384 + d] = T;
    float4v hv = {h[0], h[1], h[2], h[3]};
    *(float4v*)(carryH + cb2 * 1536 + d * 4) = hv;
}

// ---------------------------------------------------------------------------
// Pass 2: one thread per chain (b,d,s), serial over NCHUNK chunks, coalesced
// per-step loads. A_k = exp(As*T_k). Writes incoming state to carryI.
// ---------------------------------------------------------------------------
__global__ __launch_bounds__(256) void k_scan_combine(const float* __restrict__ carryT,
                                                      const float* __restrict__ carryH,
                                                      const float* __restrict__ A_log,
                                                      float* __restrict__ carryI) {
    int c   = blockIdx.x * 256 + threadIdx.x;   // 0..12287
    int b   = c / 1536;
    int rem = c - b * 1536;                     // d*4+s
    int d   = rem >> 2;
    float As = -__expf(A_log[rem]);
    float hrun = 0.f;
    #pragma unroll 4
    for (int k = 0; k < NCHUNK; k++) {
        size_t o = (size_t)k * BB + b;
        float T  = carryT[o * 384 + d];
        float Hk = carryH[o * 1536 + rem];
        carryI[o * 1536 + rem] = hrun;
        hrun = __expf(As * T) * hrun + Hk;
    }
}

// ---------------------------------------------------------------------------
// Pass 3: decay-only correction. Linearity of the recurrence gives
//   h_total[l] = h_local[l] + P[l]*h_in,  P[l] = prod_{j<=l} da[j],
// so  y[l] = (y_local[l] + (P[l]*h_in)·C[l]) * siluz[l]   (z pre-gated in
// the GEMM epilogue). C row read as one float4v (16B-aligned).
// ---------------------------------------------------------------------------
__global__ __launch_bounds__(384) void k_scan_corr(const uint* __restrict__ dyb,
                                                   const ushort* __restrict__ xz,
                                                   const float* __restrict__ ccol,
                                                   const float* __restrict__ A_log,
                                                   const float* __restrict__ carryI,
                                                   ushort* __restrict__ y) {
    int d     = threadIdx.x;
    int chunk = blockIdx.x;
    int b     = blockIdx.y;
    __shared__ float Crow[CLEN][DSTATE];
    size_t mbase = (size_t)b * LL + (size_t)chunk * CLEN;
    if (d < CLEN * DSTATE) {
        Crow[d >> 2][d & 3] = ccol[mbase * 4 + d];
    }
    float As[DSTATE];
    #pragma unroll
    for (int s = 0; s < DSTATE; s++) As[s] = -__expf(A_log[d * DSTATE + s]);
    bool fastA = as_is_harmonic(As);
    float4v hv = *(const float4v*)(carryI + ((size_t)chunk * BB + b) * 1536 + d * 4);
    float hc[DSTATE];
    #pragma unroll
    for (int s = 0; s < DSTATE; s++) hc[s] = hv[s];
    __syncthreads();
    #pragma unroll 8
    for (int l = 0; l < CLEN; l++) {
        size_t m = mbase + l;
        uint dv = dyb[m * DINNER + d];
        float dtvv = b2f((ushort)(dv >> 16));
        float ylv  = b2f((ushort)(dv & 0xffffu));
        float4v cv4 = *(const float4v*)&Crow[l][0];     // one ds_read_b128
        float da[DSTATE];
        if (fastA) {
            float p = __expf(dtvv * As[0]);
            da[0] = p; da[1] = p * p; da[2] = da[1] * p; da[3] = da[2] * p;
        } else {
            #pragma unroll
            for (int s = 0; s < DSTATE; s++) da[s] = __expf(dtvv * As[s]);
        }
        float corr = 0.f;
        #pragma unroll
        for (int s = 0; s < DSTATE; s++) {
            hc[s] *= da[s];
            corr  += hc[s] * cv4[s];
        }
        float yv = ylv + corr;
        float zs = b2f(xz[m * 768 + DINNER + d]);   // silu(z) pre-applied
        yv *= zs;
        y[m * DINNER + d] = f2b(yv);
    }
}

// ---------------------------------------------------------------------------
// Tail: low-rank (U,V) + residual(h0b, bf16) + LayerNorm; LDS-staged
// coalesced (B,C,L) writes.
// ---------------------------------------------------------------------------
__global__ __launch_bounds__(256) void k_tail(const ushort* __restrict__ h1b,
                                              const ushort* __restrict__ h0b,
                                              const float* __restrict__ U,
                                              const float* __restrict__ V,
                                              const float* __restrict__ g,
                                              const float* __restrict__ be,
                                              float* __restrict__ out) {
    __shared__ float tile[EMBED * 65];
    int tid  = threadIdx.x;
    int lane = tid & 63;
    int wave = tid >> 6;
    int b  = blockIdx.y;
    int l0 = blockIdx.x * 64;
    for (int t = 0; t < 16; t++) {
        int lloc = wave * 16 + t;
        size_t m = (size_t)b * LL + l0 + lloc;
        float hv[3];
        #pragma unroll
        for (int i = 0; i < 3; i++) hv[i] = b2f(h1b[m * EMBED + lane + 64 * i]);
        float r[RANK];
        #pragma unroll
        for (int j = 0; j < RANK; j++) {
            float p = 0.f;
            #pragma unroll
            for (int i = 0; i < 3; i++) p += hv[i] * U[j * EMBED + lane + 64 * i];
            #pragma unroll
            for (int off = 1; off < 64; off <<= 1) p += __shfl_xor(p, off);
            r[j] = p;
        }
        float u[3], s1 = 0.f, s2 = 0.f;
        #pragma unroll
        for (int i = 0; i < 3; i++) {
            int c = lane + 64 * i;
            float v = r[0] * V[c * 4 + 0] + r[1] * V[c * 4 + 1]
                    + r[2] * V[c * 4 + 2] + r[3] * V[c * 4 + 3];
            u[i] = v + b2f(h0b[m * EMBED + c]);
            s1 += u[i];
            s2 += u[i] * u[i];
        }
        #pragma unroll
        for (int off = 1; off < 64; off <<= 1) {
            s1 += __shfl_xor(s1, off);
            s2 += __shfl_xor(s2, off);
        }
        float mean = s1 * (1.f / EMBED);
        float var  = s2 * (1.f / EMBED) - mean * mean;
        float inv  = rsqrtf(var + 1e-5f);
        #pragma unroll
        for (int i = 0; i < 3; i++) {
            int c = lane + 64 * i;
            tile[c * 65 + lloc] = (u[i] - mean) * inv * g[c] + be[c];
        }
    }
    __syncthreads();
    for (int i = tid; i < EMBED * 64; i += 256) {
        int c = i >> 6, l = i & 63;
        out[((size_t)(b * EMBED + c)) * LL + l0 + l] = tile[c * 65 + l];
    }
}

// ---------------------------------------------------------------------------
extern "C" void kernel_launch(void* const* d_in, const int* in_sizes, int n_in,
                              void* d_out, int out_size, void* d_ws, size_t ws_size,
                              hipStream_t stream) {
    const float* x          = (const float*)d_in[0];
    const float* in_proj_w  = (const float*)d_in[1];
    const float* conv_w     = (const float*)d_in[2];
    const float* conv_b     = (const float*)d_in[3];
    const float* x_proj_w   = (const float*)d_in[4];
    const float* dt_proj_w  = (const float*)d_in[5];
    const float* dt_proj_b  = (const float*)d_in[6];
    const float* A_log      = (const float*)d_in[7];
    const float* Dp         = (const float*)d_in[8];
    const float* out_proj_w = (const float*)d_in[9];
    const float* U_w        = (const float*)d_in[10];
    const float* V_w        = (const float*)d_in[11];
    const float* ln_g       = (const float*)d_in[12];
    const float* ln_b       = (const float*)d_in[13];
    float* out = (float*)d_out;

    // Workspace layout. (ccol reuses the old xdb32 slot; xa16 eliminated)
    float* ws    = (float*)d_ws;
    float* ccol  = ws;                                     // NBL*4 f32
    float* carryT = ws + (size_t)NBL * 32;                 // NCHUNK*8*384 f32
    float* carryH = carryT + (size_t)NCHUNK * BB * DINNER; // NCHUNK*8*1536 f32
    float* carryI = carryH + (size_t)NCHUNK * BB * DINNER * DSTATE;
    ushort* xz16   = (ushort*)(carryI + (size_t)NCHUNK * BB * DINNER * DSTATE);
    ushort* yb     = xz16   + (size_t)NBL * 768;
    ushort* h0b    = yb     + (size_t)NBL * DINNER;
    ushort* h1b    = h0b    + (size_t)NBL * EMBED;
    uint*   dyb    = (uint*)(h1b + (size_t)NBL * EMBED);   // NBL*384 u32 (dt|yl)
    ushort* wi     = (ushort*)(dyb + (size_t)NBL * DINNER); // 2*768*192
    ushort* wo     = wi     + (size_t)NMIX * 768 * EMBED;  // 2*192*384
    ushort* xpwb   = wo     + (size_t)NMIX * EMBED * DINNER; // 2*32*384
    ushort* dtwpad = xpwb   + (size_t)NMIX * 32 * 384;       // 2*384*32
    float*  cwt    = (float*)(dtwpad + (size_t)NMIX * 384 * 32); // 2*4*384 f32

    // fused weight prep + input transpose (one launch)
    k_prep<<<PREP_BLKS + TRAN_BLKS, 256, 0, stream>>>(
        x, in_proj_w, out_proj_w, x_proj_w, dt_proj_w, conv_w,
        wi, wo, xpwb, dtwpad, cwt, h0b);

    const ushort* hinb = h0b;
    for (int mix = 0; mix < NMIX; mix++) {
        const float* Alg  = A_log + (size_t)mix * DINNER * DSTATE;
        const ushort* dtwm = dtwpad + (size_t)mix * 384 * 32;
        const float* dtbm = dt_proj_b + mix * DINNER;

        // in_proj -> xz bf16 (NBL,768); z half pre-gated with silu.
        // dim3(256 m-tiles, 6 n-tiles): A-panel sharers land on one XCD.
        k_gemm_bf16<128, 2, true><<<dim3(NBL / 128, 768 / 128), 256, 0, stream>>>(
            hinb, EMBED, wi + (size_t)mix * 768 * EMBED, EMBED, xz16, 768, EMBED);
        // chunked scan with fused conv+silu AND x_proj: local -> combine -> corr
        k_scan_local<<<dim3(NCHUNK, BB), 384, 0, stream>>>(
            xz16, cwt + (size_t)mix * DCONV * DINNER, conv_b + mix * DINNER,
            xpwb + (size_t)mix * 32 * 384, dtwm, dtbm, Alg,
            Dp + mix * DINNER, carryT, carryH, ccol, dyb);
        k_scan_combine<<<(BB * DINNER * DSTATE) / 256, 256, 0, stream>>>(
            carryT, carryH, Alg, carryI);
        k_scan_corr<<<dim3(NCHUNK, BB), 384, 0, stream>>>(
            dyb, xz16, ccol, Alg, carryI, yb);
        // out_proj -> h1b bf16. dim3(256 m-tiles, 3 n-tiles).
        k_gemm_bf16<64, 1, false><<<dim3(NBL / 128, EMBED / 64), 256, 0, stream>>>(
            yb, DINNER, wo + (size_t)mix * EMBED * DINNER, DINNER, h1b, EMBED, DINNER);
        hinb = h1b;
    }

    // tail: low-rank + residual(h0b) + LayerNorm -> out (B,C,H,W)
    k_tail<<<dim3(LL / 64, BB), 256, 0, stream>>>(h1b, h0b, U_w, V_w, ln_g, ln_b, out);
}

// Round 16
// 352.761 us; speedup vs baseline: 1.0231x; 1.0231x over previous
//
#include <hip/hip_runtime.h>
#include <hip/hip_bf16.h>
#include <cstdint>

// Problem constants
#define EMBED   192
#define DINNER  384
#define DSTATE  4
#define DCONV   4
#define DTRANK  12
#define NMIX    2
#define RANK    4
#define BB      8
#define LL      4096            // H*W = 64*64
#define NBL     (BB*LL)         // 32768 rows
#define NCHUNK  128
#define CLEN    32              // LL / NCHUNK (verified optimum; 16 regressed)
#define RSTR    36              // rows LDS stride (pad: b128-aligned, <=2-way banks)
#define XSTR    392             // xa LDS tile stride (384+8: <=2-way banks)

typedef __attribute__((ext_vector_type(8))) short short8;
typedef __attribute__((ext_vector_type(4))) float float4v;

static __device__ __forceinline__ ushort f2b(float f) {
    __hip_bfloat16 h = __float2bfloat16(f);
    return *(ushort*)&h;
}
static __device__ __forceinline__ float b2f(ushort u) {
    __hip_bfloat16 h;
    *(ushort*)&h = u;
    return __bfloat162float(h);
}
static __device__ __forceinline__ float bs2f(short s) {
    ushort u = (ushort)s;
    return b2f(u);
}

// ---------------------------------------------------------------------------
// Fused weight prep + input transpose (ONE launch):
// blocks [0, PREP_BLKS): wi cast | wo cast | xpw pad | dtw pad | cwT
// blocks [PREP_BLKS, +6144): (B,C,L) -> (B,L,C) bf16 transpose (h0b).
// Branch is block-uniform; __syncthreads only on the transpose path.
// ---------------------------------------------------------------------------
#define PREP_N0 294912
#define PREP_N1 147456
#define PREP_N2 24576
#define PREP_N3 24576
#define PREP_N4 3072
#define PREP_BLKS ((PREP_N0 + PREP_N1 + PREP_N2 + PREP_N3 + PREP_N4) / 256)   // 1932
#define TRAN_BLKS ((LL / 32) * (EMBED / 32) * BB)                              // 6144
__global__ __launch_bounds__(256) void k_prep(const float* __restrict__ x,
                                              const float* __restrict__ in_proj_w,
                                              const float* __restrict__ out_proj_w,
                                              const float* __restrict__ x_proj_w,
                                              const float* __restrict__ dt_proj_w,
                                              const float* __restrict__ conv_w,
                                              ushort* __restrict__ wi,
                                              ushort* __restrict__ wo,
                                              ushort* __restrict__ xpwb,
                                              ushort* __restrict__ dtwpad,
                                              float* __restrict__ cwt,
                                              ushort* __restrict__ h0b) {
    __shared__ float tile[32][33];
    int bid = blockIdx.x;
    if (bid < PREP_BLKS) {
        int i = bid * 256 + threadIdx.x;
        if (i < PREP_N0) {
            wi[i] = f2b(in_proj_w[i]);
            return;
        }
        i -= PREP_N0;
        if (i < PREP_N1) {
            wo[i] = f2b(out_proj_w[i]);
            return;
        }
        i -= PREP_N1;
        if (i < PREP_N2) {
            int mix = i / (32 * 384);
            int rem = i % (32 * 384);
            int e = rem / 384, k = rem % 384;
            xpwb[i] = (e < 20) ? f2b(x_proj_w[(size_t)mix * 20 * 384 + e * 384 + k])
                               : (ushort)0;
            return;
        }
        i -= PREP_N2;
        if (i < PREP_N3) {
            // dtwpad[mix][d][r], r zero-padded 12..31 (K=32 exact)
            int mix = i / (384 * 32);
            int rem = i % (384 * 32);
            int n = rem / 32, r = rem % 32;
            dtwpad[i] = (r < DTRANK)
                ? f2b(dt_proj_w[(size_t)mix * 384 * DTRANK + n * DTRANK + r])
                : (ushort)0;
            return;
        }
        i -= PREP_N3;
        if (i < PREP_N4) {
            int mix = i / (DCONV * DINNER);
            int rem = i % (DCONV * DINNER);
            int k = rem / DINNER, d = rem % DINNER;
            cwt[i] = conv_w[(size_t)mix * DINNER * DCONV + d * DCONV + k];
        }
        return;
    }
    // transpose path: decode (x=LL/32 fastest, y=EMBED/32, z=BB)
    int tb   = bid - PREP_BLKS;
    int xb   = tb % (LL / 32);
    int rest = tb / (LL / 32);
    int cbk  = rest % (EMBED / 32);
    int b    = rest / (EMBED / 32);
    int l0 = xb * 32;
    int c0 = cbk * 32;
    int tx = threadIdx.x & 31;
    int ty = threadIdx.x >> 5;      // 0..7
    #pragma unroll
    for (int i = 0; i < 4; i++) {
        int c = c0 + ty + i * 8;
        tile[ty + i * 8][tx] = x[((size_t)b * EMBED + c) * LL + l0 + tx];
    }
    __syncthreads();
    #pragma unroll
    for (int i = 0; i < 4; i++) {
        int l = l0 + ty + i * 8;
        h0b[((size_t)b * LL + l) * EMBED + c0 + tx] = f2b(tile[tx][ty + i * 8]);
    }
}

// ---------------------------------------------------------------------------
// bf16 MFMA GEMM, NT: C[m,n] = sum_k A[m,k]*B[n,k]. M=32768.
// Grid dim3(256 m-tiles, NTL n-tiles), M in blockIdx.x: A-panel sharers land
// on the same XCD (bid%8 == M%8 since gridDim.x%8==0) -> panel HBM-fetched
// once per XCD L2 (verified r7: FETCH 76MB -> 11.5MB).
// Reg-prefetch k+1 before the MFMAs + LDS double-buffer, ONE barrier/iter
// (verified r8: 381 -> 369.6).
// TN in {128 (WRN=2), 64 (WRN=1)}. BK=32. Writes bf16 Cb.
// SILUZ: apply silu to cols >= DINNER before the store (pre-gated z).
// ---------------------------------------------------------------------------
template<int TN, int WRN, bool SILUZ>
__global__ __launch_bounds__(256) void k_gemm_bf16(const ushort* __restrict__ A, int lda,
                                                   const ushort* __restrict__ Bw, int ldb,
                                                   ushort* __restrict__ Cb, int ldcb,
                                                   int K) {
    constexpr int WRM = 4 / WRN;
    constexpr int WM  = 128 / WRM;
    constexpr int MT  = WM / 16;
    constexpr int NBU = TN / 64;
    __shared__ ushort As[2][128][40];
    __shared__ ushort Bs[2][TN][40];
    int tid  = threadIdx.x;
    int lane = tid & 63;
    int wave = tid >> 6;
    int mcol = lane & 15;
    int quad = lane >> 4;
    int wmo = (wave / WRN) * WM;
    int wno = (wave % WRN) * 64;
    int m0 = blockIdx.x * 128;
    int n0 = blockIdx.y * TN;

    float4v acc[MT][4];
    #pragma unroll
    for (int i = 0; i < MT; i++)
        #pragma unroll
        for (int j = 0; j < 4; j++)
            acc[i][j] = (float4v){0.f, 0.f, 0.f, 0.f};

    short8 pa[2], pb[NBU];
    // prologue: stage k=0 into buffer 0
    #pragma unroll
    for (int i = 0; i < 2; i++) {
        int idx = tid + i * 256, r = idx >> 2, sg = idx & 3;
        pa[i] = *(const short8*)(A + (size_t)(m0 + r) * lda + sg * 8);
    }
    #pragma unroll
    for (int i = 0; i < NBU; i++) {
        int idx = tid + i * 256, r = idx >> 2, sg = idx & 3;
        pb[i] = *(const short8*)(Bw + (size_t)(n0 + r) * ldb + sg * 8);
    }
    #pragma unroll
    for (int i = 0; i < 2; i++) {
        int idx = tid + i * 256;
        *(short8*)&As[0][idx >> 2][(idx & 3) * 8] = pa[i];
    }
    #pragma unroll
    for (int i = 0; i < NBU; i++) {
        int idx = tid + i * 256;
        *(short8*)&Bs[0][idx >> 2][(idx & 3) * 8] = pb[i];
    }
    __syncthreads();

    int cur = 0;
    for (int k0 = 0; k0 < K; k0 += 32) {
        bool more = (k0 + 32) < K;
        if (more) {
            // issue next-tile loads early: latency hides under ds_read+MFMA
            #pragma unroll
            for (int i = 0; i < 2; i++) {
                int idx = tid + i * 256, r = idx >> 2, sg = idx & 3;
                pa[i] = *(const short8*)(A + (size_t)(m0 + r) * lda + k0 + 32 + sg * 8);
            }
            #pragma unroll
            for (int i = 0; i < NBU; i++) {
                int idx = tid + i * 256, r = idx >> 2, sg = idx & 3;
                pb[i] = *(const short8*)(Bw + (size_t)(n0 + r) * ldb + k0 + 32 + sg * 8);
            }
        }
        short8 av[MT], bv[4];
        #pragma unroll
        for (int i = 0; i < MT; i++)
            av[i] = *(const short8*)&As[cur][wmo + i * 16 + mcol][quad * 8];
        #pragma unroll
        for (int j = 0; j < 4; j++)
            bv[j] = *(const short8*)&Bs[cur][wno + j * 16 + mcol][quad * 8];
        #pragma unroll
        for (int i = 0; i < MT; i++)
            #pragma unroll
            for (int j = 0; j < 4; j++)
                acc[i][j] = __builtin_amdgcn_mfma_f32_16x16x32_bf16(
                    av[i], bv[j], acc[i][j], 0, 0, 0);
        if (more) {
            #pragma unroll
            for (int i = 0; i < 2; i++) {
                int idx = tid + i * 256;
                *(short8*)&As[cur ^ 1][idx >> 2][(idx & 3) * 8] = pa[i];
            }
            #pragma unroll
            for (int i = 0; i < NBU; i++) {
                int idx = tid + i * 256;
                *(short8*)&Bs[cur ^ 1][idx >> 2][(idx & 3) * 8] = pb[i];
            }
        }
        __syncthreads();   // read-done (cur) + write-visible (cur^1), 1/iter
        cur ^= 1;
    }

    #pragma unroll
    for (int i = 0; i < MT; i++) {
        int rbase = m0 + wmo + i * 16 + quad * 4;
        #pragma unroll
        for (int j = 0; j < 4; j++) {
            int col = n0 + wno + j * 16 + mcol;
            #pragma unroll
            for (int r = 0; r < 4; r++) {
                float v = acc[i][j][r];
                if (SILUZ && col >= DINNER) v = v / (1.f + __expf(-v));
                Cb[(size_t)(rbase + r) * ldcb + col] = f2b(v);
            }
        }
    }
}

// ---------------------------------------------------------------------------
// In-block dt tile via MFMA: dt[l][d] = softplus(rows[l][0:12] . dtw[d][0:12]
// + bias[d]), K padded to 32. Result -> LDS bf16.
// ---------------------------------------------------------------------------
static __device__ __forceinline__ void dt_mfma_tile(const float* __restrict__ rows,
                                                    const ushort* __restrict__ dtwpad,
                                                    const float* __restrict__ dtb,
                                                    ushort* __restrict__ dtS,
                                                    int wave, int lane) {
    int mcol = lane & 15;
    int quad = lane >> 4;
    #pragma unroll
    for (int nt = 0; nt < 4; nt++) {
        int n = wave * 64 + nt * 16 + mcol;
        short8 bv = *(const short8*)(dtwpad + (size_t)n * 32 + quad * 8);
        float bias = dtb[n];
        #pragma unroll
        for (int mt = 0; mt < CLEN / 16; mt++) {
            float4v a0 = *(const float4v*)&rows[(mt * 16 + mcol) * RSTR + quad * 8];
            float4v a1 = *(const float4v*)&rows[(mt * 16 + mcol) * RSTR + quad * 8 + 4];
            short8 av;
            #pragma unroll
            for (int j = 0; j < 4; j++) {
                av[j]     = (short)f2b(a0[j]);
                av[j + 4] = (short)f2b(a1[j]);
            }
            float4v acc = (float4v){0.f, 0.f, 0.f, 0.f};
            acc = __builtin_amdgcn_mfma_f32_16x16x32_bf16(av, bv, acc, 0, 0, 0);
            #pragma unroll
            for (int r = 0; r < 4; r++) {
                float s = acc[r] + bias;
                float sp = fmaxf(s, 0.f) + __logf(1.f + __expf(-fabsf(s)));
                dtS[(mt * 16 + quad * 4 + r) * DINNER + n] = f2b(sp);
            }
        }
    }
}

// Adaptive state-decay: if As = (1,2,3,4)*As0 (true for this model's A_log),
// 4 exps collapse to 1 exp + 3 muls. Generic fallback otherwise.
static __device__ __forceinline__ bool as_is_harmonic(const float* As) {
    return fabsf(As[1] - 2.f * As[0]) <= 1e-5f * fabsf(As[1]) + 1e-12f
        && fabsf(As[2] - 3.f * As[0]) <= 1e-5f * fabsf(As[2]) + 1e-12f
        && fabsf(As[3] - 4.f * As[0]) <= 1e-5f * fabsf(As[3]) + 1e-12f;
}

// ---------------------------------------------------------------------------
// Chunked scan pass 1, with conv+silu AND x_proj fused in (r12/r14 form,
// verified best 353.3us; r11 reg-packing, r13 CLEN=16, r15 float4v LDS
// reads all regressed — this kernel is at its structural floor).
// Thread d owns column d; slides the causal 4-tap window over coalesced
// row-reads of xz's x-half (3 halo rows from previous chunk, zero at chunk
// 0). Bit-identical bf16 rounding to the original k_conv_silu path.
// Then: waves 0-3 compute rows[l][e] = xaS[l,:]·xpwb[e,:] (f32 acc to LDS),
// C-cols -> compact ccol, dt tile via MFMA, local scan (packed dt|y_local).
// ---------------------------------------------------------------------------
__global__ __launch_bounds__(384) void k_scan_local(const ushort* __restrict__ xz,
                                                    const float* __restrict__ cwt,
                                                    const float* __restrict__ cb,
                                                    const ushort* __restrict__ xpwb,
                                                    const ushort* __restrict__ dtwpad,
                                                    const float* __restrict__ dtb,
                                                    const float* __restrict__ A_log,
                                                    const float* __restrict__ Dp,
                                                    float* __restrict__ carryT,
                                                    float* __restrict__ carryH,
                                                    float* __restrict__ ccol,
                                                    uint* __restrict__ dyb) {
    int d     = threadIdx.x;
    int lane  = d & 63;
    int wave  = d >> 6;
    int chunk = blockIdx.x;
    int b     = blockIdx.y;
    __shared__ ushort xaS[CLEN][XSTR];
    __shared__ float rows[CLEN * RSTR];
    __shared__ ushort dtS[CLEN * DINNER];
    size_t mbase = (size_t)b * LL + (size_t)chunk * CLEN;

    // fused conv+silu staging: column d, sliding 4-tap causal window
    {
        float w0 = cwt[0 * DINNER + d], w1 = cwt[1 * DINNER + d];
        float w2 = cwt[2 * DINNER + d], w3 = cwt[3 * DINNER + d];
        float bias = cb[d];
        float r0 = 0.f, r1 = 0.f, r2 = 0.f;
        if (chunk > 0) {
            r0 = b2f(xz[(mbase - 3) * 768 + d]);
            r1 = b2f(xz[(mbase - 2) * 768 + d]);
            r2 = b2f(xz[(mbase - 1) * 768 + d]);
        }
        #pragma unroll 8
        for (int l = 0; l < CLEN; l++) {
            float cur = b2f(xz[(mbase + l) * 768 + d]);
            float a = bias + w0 * r0 + w1 * r1 + w2 * r2 + w3 * cur;
            xaS[l][d] = f2b(a / (1.f + __expf(-a)));
            r0 = r1; r1 = r2; r2 = cur;
        }
    }
    float As[DSTATE];
    #pragma unroll
    for (int s = 0; s < DSTATE; s++) As[s] = -__expf(A_log[d * DSTATE + s]);
    bool fastA = as_is_harmonic(As);
    float Dd = Dp[d];
    __syncthreads();

    // fused x_proj: rows[l][e] = sum_k xaS[l][k] * xpwb[e][k]  (e<32)
    if (wave < (CLEN / 16) * 2) {
        int mi = wave >> 1, ni = wave & 1;
        int mcol = lane & 15, quad = lane >> 4;
        float4v acc = (float4v){0.f, 0.f, 0.f, 0.f};
        #pragma unroll
        for (int k0 = 0; k0 < 384; k0 += 32) {
            short8 av = *(const short8*)&xaS[mi * 16 + mcol][k0 + quad * 8];
            short8 bv = *(const short8*)(xpwb + (size_t)(ni * 16 + mcol) * 384
                                         + k0 + quad * 8);
            acc = __builtin_amdgcn_mfma_f32_16x16x32_bf16(av, bv, acc, 0, 0, 0);
        }
        #pragma unroll
        for (int r = 0; r < 4; r++)
            rows[(mi * 16 + quad * 4 + r) * RSTR + ni * 16 + mcol] = acc[r];
    }
    __syncthreads();
    // compact C-cols for pass 3 (cols 16..19 of rows)
    if (d < CLEN * DSTATE) {
        int l = d >> 2, s = d & 3;
        ccol[(mbase + l) * 4 + s] = rows[l * RSTR + DTRANK + DSTATE + s];
    }
    dt_mfma_tile(rows, dtwpad, dtb, dtS, wave, lane);
    __syncthreads();

    float h[DSTATE] = {0.f, 0.f, 0.f, 0.f};
    float T = 0.f;
    #pragma unroll 8
    for (int l = 0; l < CLEN; l++) {
        ushort dtu = dtS[l * DINNER + d];
        float dtvv = b2f(dtu);
        float xav  = b2f(xaS[l][d]);
        float du   = dtvv * xav;
        T += dtvv;
        const float* row = &rows[l * RSTR];
        float da[DSTATE];
        if (fastA) {
            float p = __expf(dtvv * As[0]);
            da[0] = p; da[1] = p * p; da[2] = da[1] * p; da[3] = da[2] * p;
        } else {
            #pragma unroll
            for (int s = 0; s < DSTATE; s++) da[s] = __expf(dtvv * As[s]);
        }
        float yv = xav * Dd;
        #pragma unroll
        for (int s = 0; s < DSTATE; s++) {
            h[s] = da[s] * h[s] + du * row[DTRANK + s];
            yv  += h[s] * row[DTRANK + DSTATE + s];
        }
        dyb[(mbase + l) * DINNER + d] = ((uint)dtu << 16) | (uint)f2b(yv);
    }
    size_t cb2 = ((size_t)chunk * BB + b);
    carryT[cb2 * 384 + d] = T;
    float4v hv = {h[0], h[1], h[2], h[3]};
    *(float4v*)(carryH + cb2 * 1536 + d * 4) = hv;
}

// ---------------------------------------------------------------------------
// Pass 2: one thread per chain (b,d,s), serial over NCHUNK chunks, coalesced
// per-step loads. A_k = exp(As*T_k). Writes incoming state to carryI.
// ---------------------------------------------------------------------------
__global__ __launch_bounds__(256) void k_scan_combine(const float* __restrict__ carryT,
                                                      const float* __restrict__ carryH,
                                                      const float* __restrict__ A_log,
                                                      float* __restrict__ carryI) {
    int c   = blockIdx.x * 256 + threadIdx.x;   // 0..12287
    int b   = c / 1536;
    int rem = c - b * 1536;                     // d*4+s
    int d   = rem >> 2;
    float As = -__expf(A_log[rem]);
    float hrun = 0.f;
    #pragma unroll 4
    for (int k = 0; k < NCHUNK; k++) {
        size_t o = (size_t)k * BB + b;
        float T  = carryT[o * 384 + d];
        float Hk = carryH[o * 1536 + rem];
        carryI[o * 1536 + rem] = hrun;
        hrun = __expf(As * T) * hrun + Hk;
    }
}

// ---------------------------------------------------------------------------
// Pass 3: decay-only correction. Linearity of the recurrence gives
//   h_total[l] = h_local[l] + P[l]*h_in,  P[l] = prod_{j<=l} da[j],
// so  y[l] = (y_local[l] + (P[l]*h_in)·C[l]) * siluz[l]   (z pre-gated in
// the GEMM epilogue). C-cols from compact ccol stream.
// ---------------------------------------------------------------------------
__global__ __launch_bounds__(384) void k_scan_corr(const uint* __restrict__ dyb,
                                                   const ushort* __restrict__ xz,
                                                   const float* __restrict__ ccol,
                                                   const float* __restrict__ A_log,
                                                   const float* __restrict__ carryI,
                                                   ushort* __restrict__ y) {
    int d     = threadIdx.x;
    int chunk = blockIdx.x;
    int b     = blockIdx.y;
    __shared__ float Crow[CLEN][DSTATE];
    size_t mbase = (size_t)b * LL + (size_t)chunk * CLEN;
    if (d < CLEN * DSTATE) {
        Crow[d >> 2][d & 3] = ccol[mbase * 4 + d];
    }
    float As[DSTATE];
    #pragma unroll
    for (int s = 0; s < DSTATE; s++) As[s] = -__expf(A_log[d * DSTATE + s]);
    bool fastA = as_is_harmonic(As);
    float4v hv = *(const float4v*)(carryI + ((size_t)chunk * BB + b) * 1536 + d * 4);
    float hc[DSTATE];
    #pragma unroll
    for (int s = 0; s < DSTATE; s++) hc[s] = hv[s];
    __syncthreads();
    #pragma unroll 8
    for (int l = 0; l < CLEN; l++) {
        size_t m = mbase + l;
        uint dv = dyb[m * DINNER + d];
        float dtvv = b2f((ushort)(dv >> 16));
        float ylv  = b2f((ushort)(dv & 0xffffu));
        float da[DSTATE];
        if (fastA) {
            float p = __expf(dtvv * As[0]);
            da[0] = p; da[1] = p * p; da[2] = da[1] * p; da[3] = da[2] * p;
        } else {
            #pragma unroll
            for (int s = 0; s < DSTATE; s++) da[s] = __expf(dtvv * As[s]);
        }
        float corr = 0.f;
        #pragma unroll
        for (int s = 0; s < DSTATE; s++) {
            hc[s] *= da[s];
            corr  += hc[s] * Crow[l][s];
        }
        float yv = ylv + corr;
        float zs = b2f(xz[m * 768 + DINNER + d]);   // silu(z) pre-applied
        yv *= zs;
        y[m * DINNER + d] = f2b(yv);
    }
}

// ---------------------------------------------------------------------------
// Tail: low-rank (U,V) + residual(h0b, bf16) + LayerNorm; LDS-staged
// coalesced (B,C,L) writes.
// ---------------------------------------------------------------------------
__global__ __launch_bounds__(256) void k_tail(const ushort* __restrict__ h1b,
                                              const ushort* __restrict__ h0b,
                                              const float* __restrict__ U,
                                              const float* __restrict__ V,
                                              const float* __restrict__ g,
                                              const float* __restrict__ be,
                                              float* __restrict__ out) {
    __shared__ float tile[EMBED * 65];
    int tid  = threadIdx.x;
    int lane = tid & 63;
    int wave = tid >> 6;
    int b  = blockIdx.y;
    int l0 = blockIdx.x * 64;
    for (int t = 0; t < 16; t++) {
        int lloc = wave * 16 + t;
        size_t m = (size_t)b * LL + l0 + lloc;
        float hv[3];
        #pragma unroll
        for (int i = 0; i < 3; i++) hv[i] = b2f(h1b[m * EMBED + lane + 64 * i]);
        float r[RANK];
        #pragma unroll
        for (int j = 0; j < RANK; j++) {
            float p = 0.f;
            #pragma unroll
            for (int i = 0; i < 3; i++) p += hv[i] * U[j * EMBED + lane + 64 * i];
            #pragma unroll
            for (int off = 1; off < 64; off <<= 1) p += __shfl_xor(p, off);
            r[j] = p;
        }
        float u[3], s1 = 0.f, s2 = 0.f;
        #pragma unroll
        for (int i = 0; i < 3; i++) {
            int c = lane + 64 * i;
            float v = r[0] * V[c * 4 + 0] + r[1] * V[c * 4 + 1]
                    + r[2] * V[c * 4 + 2] + r[3] * V[c * 4 + 3];
            u[i] = v + b2f(h0b[m * EMBED + c]);
            s1 += u[i];
            s2 += u[i] * u[i];
        }
        #pragma unroll
        for (int off = 1; off < 64; off <<= 1) {
            s1 += __shfl_xor(s1, off);
            s2 += __shfl_xor(s2, off);
        }
        float mean = s1 * (1.f / EMBED);
        float var  = s2 * (1.f / EMBED) - mean * mean;
        float inv  = rsqrtf(var + 1e-5f);
        #pragma unroll
        for (int i = 0; i < 3; i++) {
            int c = lane + 64 * i;
            tile[c * 65 + lloc] = (u[i] - mean) * inv * g[c] + be[c];
        }
    }
    __syncthreads();
    for (int i = tid; i < EMBED * 64; i += 256) {
        int c = i >> 6, l = i & 63;
        out[((size_t)(b * EMBED + c)) * LL + l0 + l] = tile[c * 65 + l];
    }
}

// ---------------------------------------------------------------------------
extern "C" void kernel_launch(void* const* d_in, const int* in_sizes, int n_in,
                              void* d_out, int out_size, void* d_ws, size_t ws_size,
                              hipStream_t stream) {
    const float* x          = (const float*)d_in[0];
    const float* in_proj_w  = (const float*)d_in[1];
    const float* conv_w     = (const float*)d_in[2];
    const float* conv_b     = (const float*)d_in[3];
    const float* x_proj_w   = (const float*)d_in[4];
    const float* dt_proj_w  = (const float*)d_in[5];
    const float* dt_proj_b  = (const float*)d_in[6];
    const float* A_log      = (const float*)d_in[7];
    const float* Dp         = (const float*)d_in[8];
    const float* out_proj_w = (const float*)d_in[9];
    const float* U_w        = (const float*)d_in[10];
    const float* V_w        = (const float*)d_in[11];
    const float* ln_g       = (const float*)d_in[12];
    const float* ln_b       = (const float*)d_in[13];
    float* out = (float*)d_out;

    // Workspace layout. (ccol reuses the old xdb32 slot; xa16 eliminated)
    float* ws    = (float*)d_ws;
    float* ccol  = ws;                                     // NBL*4 f32
    float* carryT = ws + (size_t)NBL * 32;                 // NCHUNK*8*384 f32
    float* carryH = carryT + (size_t)NCHUNK * BB * DINNER; // NCHUNK*8*1536 f32
    float* carryI = carryH + (size_t)NCHUNK * BB * DINNER * DSTATE;
    ushort* xz16   = (ushort*)(carryI + (size_t)NCHUNK * BB * DINNER * DSTATE);
    ushort* yb     = xz16   + (size_t)NBL * 768;
    ushort* h0b    = yb     + (size_t)NBL * DINNER;
    ushort* h1b    = h0b    + (size_t)NBL * EMBED;
    uint*   dyb    = (uint*)(h1b + (size_t)NBL * EMBED);   // NBL*384 u32 (dt|yl)
    ushort* wi     = (ushort*)(dyb + (size_t)NBL * DINNER); // 2*768*192
    ushort* wo     = wi     + (size_t)NMIX * 768 * EMBED;  // 2*192*384
    ushort* xpwb   = wo     + (size_t)NMIX * EMBED * DINNER; // 2*32*384
    ushort* dtwpad = xpwb   + (size_t)NMIX * 32 * 384;       // 2*384*32
    float*  cwt    = (float*)(dtwpad + (size_t)NMIX * 384 * 32); // 2*4*384 f32

    // fused weight prep + input transpose (one launch)
    k_prep<<<PREP_BLKS + TRAN_BLKS, 256, 0, stream>>>(
        x, in_proj_w, out_proj_w, x_proj_w, dt_proj_w, conv_w,
        wi, wo, xpwb, dtwpad, cwt, h0b);

    const ushort* hinb = h0b;
    for (int mix = 0; mix < NMIX; mix++) {
        const float* Alg  = A_log + (size_t)mix * DINNER * DSTATE;
        const ushort* dtwm = dtwpad + (size_t)mix * 384 * 32;
        const float* dtbm = dt_proj_b + mix * DINNER;

        // in_proj -> xz bf16 (NBL,768); z half pre-gated with silu.
        // dim3(256 m-tiles, 6 n-tiles): A-panel sharers land on one XCD.
        k_gemm_bf16<128, 2, true><<<dim3(NBL / 128, 768 / 128), 256, 0, stream>>>(
            hinb, EMBED, wi + (size_t)mix * 768 * EMBED, EMBED, xz16, 768, EMBED);
        // chunked scan with fused conv+silu AND x_proj: local -> combine -> corr
        k_scan_local<<<dim3(NCHUNK, BB), 384, 0, stream>>>(
            xz16, cwt + (size_t)mix * DCONV * DINNER, conv_b + mix * DINNER,
            xpwb + (size_t)mix * 32 * 384, dtwm, dtbm, Alg,
            Dp + mix * DINNER, carryT, carryH, ccol, dyb);
        k_scan_combine<<<(BB * DINNER * DSTATE) / 256, 256, 0, stream>>>(
            carryT, carryH, Alg, carryI);
        k_scan_corr<<<dim3(NCHUNK, BB), 384, 0, stream>>>(
            dyb, xz16, ccol, Alg, carryI, yb);
        // out_proj -> h1b bf16. dim3(256 m-tiles, 3 n-tiles).
        k_gemm_bf16<64, 1, false><<<dim3(NBL / 128, EMBED / 64), 256, 0, stream>>>(
            yb, DINNER, wo + (size_t)mix * EMBED * DINNER, DINNER, h1b, EMBED, DINNER);
        hinb = h1b;
    }

    // tail: low-rank + residual(h0b) + LayerNorm -> out (B,C,H,W)
    k_tail<<<dim3(LL / 64, BB), 256, 0, stream>>>(h1b, h0b, U_w, V_w, ln_g, ln_b, out);
}